// Round 8
// baseline (290.475 us; speedup 1.0000x reference)
//
#include <hip/hip_runtime.h>

// ---------------------------------------------------------------------------
// GCN block: 3x (MFMA bf16 GEMM -> degree-normalized aggregate), resid, relu.
// 9 dispatches: memset(cursors) | scatter(fixed-CAP buckets) |
//   sort(+pad,+dinv,+rp2) | gemm1 | agg1 | gemm2 | agg2 | gemm3 | agg3
// R20: concurrency test on agg. Evidence R16-R19: agg time invariant under
// col pipelining, VMEM width, HBM traffic, chain shape => test the last
// hypothesis: outstanding-request concurrency. k_agg2n = TWO nodes/wave,
// all col+gather loads for both nodes batch-issued before one wait
// (~12-16 cols + 8-16 gathers in flight vs ~11). Wave count halves (50K).
// Tier-2 (deg 17..32) issue conditional per node (no sentinel VALU bloat);
// deg>32 drained by rare 32-bursts. Reduce: shfl_xor(16/32) puts full sums
// in ALL lanes; lanes 0-15 write node0, lanes 16-31 write node1.
// Also: k_sort single-pass (bucket packed -> 20 regs/thread, hist+fill from
// regs, fallback if cnt>5120) deletes a 6.5MB dependent re-read.
// R18 lesson: XCD shard halved FETCH but doubled L2 transactions (32B
// sub-line passes) -- slower. R15 lesson: direct CSR fill = 104MB write amp.
// R16: single-pass scatter. R14: direct col loads. R9: dinv in GEMM epilogue.
// ---------------------------------------------------------------------------

#define LB 8
#define BKN 256
#define CHUNK 4096
#define EPT 16                     // edges per thread in scatter (CHUNK/256)
#define SEPT 20                    // packed entries per thread in sort regs
#define CAP 8192                   // packed slots per bucket (mean fill 4092)
#define PADS 3                     // segment padding to x4
#define CAPCOL (CAP + BKN * PADS)  // padded col region per bucket

typedef unsigned short ushort_t;
typedef __attribute__((ext_vector_type(8))) short bf16x8;
typedef __attribute__((ext_vector_type(4))) float f32x4;

__device__ __forceinline__ unsigned f2bf(float f) {
    unsigned u = __builtin_bit_cast(unsigned, f);
    return (u + 0x7FFFu + ((u >> 16) & 1u)) >> 16;   // RNE
}
__device__ __forceinline__ float bf2f(ushort_t h) {
    unsigned u = ((unsigned)h) << 16;
    return __builtin_bit_cast(float, u);
}
__device__ __forceinline__ float bflo(unsigned u) {
    return __builtin_bit_cast(float, u << 16);
}
__device__ __forceinline__ float bfhi(unsigned u) {
    return __builtin_bit_cast(float, u & 0xFFFF0000u);
}

// per-block int64-vs-int32 probe (sampled; same result in every block)
__device__ int detect_f64(const int* ei, int E, int* sflag) {
    if (threadIdx.x == 0) *sflag = 0;
    __syncthreads();
    const unsigned* raw = (const unsigned*)ei;
    int dwords = min(2 * E, 512);
    int any = 0;
    for (int i = threadIdx.x; i < dwords; i += blockDim.x)
        if ((i & 1) && raw[i]) any = 1;
    if (any) atomicOr(sflag, 1);
    __syncthreads();
    return !*sflag;   // all sampled high words zero => int64
}

// ---- scatter: partition edges into fixed-CAP bucket regions ---------------
// packed[b*CAP + cursor] = (src<<8 | dst&255); cursor is RELATIVE (0-init).
// Single pass over ei: each thread keeps its EPT edges in (unrolled) regs.
__global__ __launch_bounds__(256) void k_scatter(
        const int* __restrict__ ei, int E,
        int* __restrict__ bucketCursor, unsigned int* __restrict__ packed) {
    __shared__ int hist[512];
    __shared__ int base[512];
    __shared__ int sflag;
    int f64 = detect_f64(ei, E, &sflag);
    int b0 = blockIdx.x * CHUNK;
    int n = min(CHUNK, E - b0);
    int tid = threadIdx.x;
    for (int i = tid; i < 512; i += 256) hist[i] = 0;
    __syncthreads();
    int dreg[EPT], sreg[EPT];
#pragma unroll
    for (int i = 0; i < EPT; i++) {
        int idx = tid + i * 256;
        if (idx < n) {
            int e = b0 + idx;
            dreg[i] = f64 ? ei[2 * (E + e)] : ei[E + e];
            sreg[i] = f64 ? ei[2 * e] : ei[e];
            atomicAdd(&hist[dreg[i] >> LB], 1);
        }
    }
    __syncthreads();
    for (int i = tid; i < 512; i += 256) {
        int c = hist[i];
        base[i] = c ? atomicAdd(&bucketCursor[i], c) : 0;
        hist[i] = 0;
    }
    __syncthreads();
#pragma unroll
    for (int i = 0; i < EPT; i++) {
        int idx = tid + i * 256;
        if (idx < n) {
            int bk = dreg[i] >> LB;
            int pos = bk * CAP + base[bk] + atomicAdd(&hist[bk], 1);
            packed[pos] = ((unsigned)sreg[i] << LB) | (unsigned)(dreg[i] & (BKN - 1));
        }
    }
}

// ---- per-bucket counting sort -> padded CSR col[], rp2, dinv --------------
// Bucket b's packed region: [b*CAP, b*CAP + cnt). Single global read: each
// thread keeps SEPT entries in regs (hist + fill from regs); fallback to the
// re-read path if cnt > 256*SEPT (practically impossible: mean 4092, 16σ).
// Node segments padded to x4 with sentinel index N; hs row N zeroed here.
__global__ __launch_bounds__(256) void k_sort(
        const unsigned int* __restrict__ packed, const int* __restrict__ bucketCursor,
        int* __restrict__ col, int2* __restrict__ rp2, float* __restrict__ dinv,
        ushort_t* __restrict__ hs, int N) {
    __shared__ int hist[BKN];
    __shared__ int s[BKN];
    __shared__ int cur[BKN];
    int tid = threadIdx.x;
    int b = blockIdx.x;
    int start = b * CAP;
    int cnt = bucketCursor[b];
    int end = start + cnt;
    int inreg = (cnt <= 256 * SEPT);
    unsigned preg[SEPT];
    hist[tid] = 0;
    __syncthreads();
    if (inreg) {
#pragma unroll
        for (int i = 0; i < SEPT; i++) {
            int e = start + tid + i * 256;
            if (e < end) {
                preg[i] = packed[e];
                atomicAdd(&hist[preg[i] & (BKN - 1)], 1);
            }
        }
    } else {
        for (int e = start + tid; e < end; e += 256)
            atomicAdd(&hist[packed[e] & (BKN - 1)], 1);
    }
    __syncthreads();
    int v = hist[tid];
    int pv = (v + PADS) & ~PADS;        // padded length (x4)
    s[tid] = pv;
    __syncthreads();
    for (int off = 1; off < 256; off <<= 1) {
        int x = (tid >= off) ? s[tid - off] : 0;
        __syncthreads();
        if (tid >= off) s[tid] += x;
        __syncthreads();
    }
    int excl = s[tid] - pv;
    int st = b * CAPCOL + excl;         // padded col base, buckets disjoint
    cur[tid] = st;
    int node = (b << LB) + tid;
    if (node < N) {
        rp2[node] = make_int2(st, st + pv);
        dinv[node] = rsqrtf((float)(v + 1));   // +1 self loop
        for (int i = v; i < pv; i++) col[st + i] = N;   // sentinel padding
    }
    if (b == 0 && tid < 64) hs[(size_t)N * 64 + tid] = 0;   // zero row N
    __syncthreads();
    if (inreg) {
#pragma unroll
        for (int i = 0; i < SEPT; i++) {
            int e = start + tid + i * 256;
            if (e < end) {
                unsigned pvk = preg[i];
                int pos = atomicAdd(&cur[pvk & (BKN - 1)], 1);
                col[pos] = (int)(pvk >> LB);
            }
        }
    } else {
        for (int e = start + tid; e < end; e += 256) {
            unsigned pvk = packed[e];
            int pos = atomicAdd(&cur[pvk & (BKN - 1)], 1);
            col[pos] = (int)(pvk >> LB);
        }
    }
}

// ---- gemm1: (N x 128) @ (128 x 64), f32 in, dinv-scaled, bf16 out ---------
__global__ __launch_bounds__(256) void k_gemm1(
        const float* __restrict__ A, const float* __restrict__ W,
        const float* __restrict__ dinv, ushort_t* __restrict__ out, int nrows) {
    const int K = 128;
    __shared__ ushort_t sWT[64 * (K + 8)];
    int tid = threadIdx.x;
    for (int i = tid; i < K * 64; i += 256) {
        int n = i & 63, k = i >> 6;
        sWT[n * (K + 8) + k] = (ushort_t)f2bf(W[i]);
    }
    __syncthreads();
    int wave = tid >> 6, lane = tid & 63;
    int quad = lane >> 4, l16 = lane & 15;
    int rowBase = blockIdx.x * 128 + wave * 32;
    f32x4 acc[2][4];
#pragma unroll
    for (int r = 0; r < 2; r++)
#pragma unroll
        for (int c = 0; c < 4; c++) acc[r][c] = (f32x4){0.f, 0.f, 0.f, 0.f};
#pragma unroll
    for (int chunk = 0; chunk < K / 32; chunk++) {
        bf16x8 afr[2];
#pragma unroll
        for (int r = 0; r < 2; r++) {
            int row = rowBase + r * 16 + l16;
            if (row >= nrows) row = nrows - 1;
            const float* ap = A + (size_t)row * K + chunk * 32 + quad * 8;
            float4 v0 = *(const float4*)ap;
            float4 v1 = *(const float4*)(ap + 4);
            bf16x8 a;
            a[0] = (short)f2bf(v0.x); a[1] = (short)f2bf(v0.y);
            a[2] = (short)f2bf(v0.z); a[3] = (short)f2bf(v0.w);
            a[4] = (short)f2bf(v1.x); a[5] = (short)f2bf(v1.y);
            a[6] = (short)f2bf(v1.z); a[7] = (short)f2bf(v1.w);
            afr[r] = a;
        }
#pragma unroll
        for (int c = 0; c < 4; c++) {
            bf16x8 bfr = __builtin_bit_cast(
                bf16x8,
                *(const uint4*)&sWT[(c * 16 + l16) * (K + 8) + chunk * 32 + quad * 8]);
#pragma unroll
            for (int r = 0; r < 2; r++)
                acc[r][c] = __builtin_amdgcn_mfma_f32_16x16x32_bf16(
                    afr[r], bfr, acc[r][c], 0, 0, 0);
        }
    }
#pragma unroll
    for (int r = 0; r < 2; r++)
#pragma unroll
        for (int i = 0; i < 4; i++) {
            int row = rowBase + r * 16 + quad * 4 + i;
            if (row < nrows) {
                float sc = dinv[row];
#pragma unroll
                for (int c = 0; c < 4; c++)
                    out[(size_t)row * 64 + c * 16 + l16] =
                        (ushort_t)f2bf(acc[r][c][i] * sc);
            }
        }
}

// ---- gemm64: (N x 64) @ (64 x 64), bf16 in, dinv-scaled, bf16 out ---------
__global__ __launch_bounds__(256) void k_gemm64(
        const ushort_t* __restrict__ A, const float* __restrict__ W,
        const float* __restrict__ dinv, ushort_t* __restrict__ out, int nrows) {
    const int K = 64;
    __shared__ ushort_t sWT[64 * (K + 8)];
    int tid = threadIdx.x;
    for (int i = tid; i < K * 64; i += 256) {
        int n = i & 63, k = i >> 6;
        sWT[n * (K + 8) + k] = (ushort_t)f2bf(W[i]);
    }
    __syncthreads();
    int wave = tid >> 6, lane = tid & 63;
    int quad = lane >> 4, l16 = lane & 15;
    int rowBase = blockIdx.x * 128 + wave * 32;
    f32x4 acc[2][4];
#pragma unroll
    for (int r = 0; r < 2; r++)
#pragma unroll
        for (int c = 0; c < 4; c++) acc[r][c] = (f32x4){0.f, 0.f, 0.f, 0.f};
#pragma unroll
    for (int chunk = 0; chunk < K / 32; chunk++) {
        bf16x8 afr[2];
#pragma unroll
        for (int r = 0; r < 2; r++) {
            int row = rowBase + r * 16 + l16;
            if (row >= nrows) row = nrows - 1;
            const ushort_t* ap = A + (size_t)row * K + chunk * 32 + quad * 8;
            afr[r] = __builtin_bit_cast(bf16x8, *(const uint4*)ap);
        }
#pragma unroll
        for (int c = 0; c < 4; c++) {
            bf16x8 bfr = __builtin_bit_cast(
                bf16x8,
                *(const uint4*)&sWT[(c * 16 + l16) * (K + 8) + chunk * 32 + quad * 8]);
#pragma unroll
            for (int r = 0; r < 2; r++)
                acc[r][c] = __builtin_amdgcn_mfma_f32_16x16x32_bf16(
                    afr[r], bfr, acc[r][c], 0, 0, 0);
        }
    }
#pragma unroll
    for (int r = 0; r < 2; r++)
#pragma unroll
        for (int i = 0; i < 4; i++) {
            int row = rowBase + r * 16 + quad * 4 + i;
            if (row < nrows) {
                float sc = dinv[row];
#pragma unroll
                for (int c = 0; c < 4; c++)
                    out[(size_t)row * 64 + c * 16 + l16] =
                        (ushort_t)f2bf(acc[r][c][i] * sc);
            }
        }
}

// ---- aggregation: TWO nodes per wave, all loads batch-issued --------------
// Row = 64 bf16 = 128B = 16 lanes x uint2. Lane group g = lane>>4 owns edge
// slot 4j+g. Per wave: node0 & node1; issue 8-16 col loads + 8-16 gathers
// covering BOTH nodes before any accumulate (concurrency ~2x R19). Tier-2
// (16<deg<=32) per-node conditional; deg>32 drained by rare 32-bursts.
// Slots >= rem map to sentinel row N (zeros, L1-hot); col overreads stay in
// the +guard region. After shfl_xor(16/32) every lane holds full sums:
// lanes 0-15 write node0, lanes 16-31 write node1.
template <int RELU, int F32OUT>
__global__ __launch_bounds__(256) void k_agg2n(
        const ushort_t* __restrict__ hs, const float* __restrict__ dinv,
        const float* __restrict__ bias, const int* __restrict__ col,
        const int2* __restrict__ rp2, const ushort_t* __restrict__ residb,
        float* __restrict__ outf, ushort_t* __restrict__ outb, int n) {
    int gw = (int)((blockIdx.x * blockDim.x + threadIdx.x) >> 6);
    int node0 = gw << 1, node1 = node0 | 1;
    if (node0 >= n) return;
    int lane = threadIdx.x & 63;
    int g = lane >> 4;                   // edge sub-slot within a 16-batch
    int c4 = lane & 15;                  // feature group: cols c4*4..c4*4+3
    bool has1 = node1 < n;
    const ushort_t* hrow = hs + (size_t)c4 * 4;
    // prologue: all independent loads in flight together
    uint2 us0 = *(const uint2*)(hs + (size_t)node0 * 64 + c4 * 4);
    uint2 us1 = has1 ? *(const uint2*)(hs + (size_t)node1 * 64 + c4 * 4)
                     : make_uint2(0u, 0u);
    float sc0 = dinv[node0];
    float sc1 = has1 ? dinv[node1] : 0.f;
    int2 r0 = rp2[node0];
    int2 r1 = has1 ? rp2[node1] : make_int2(0, 0);
    int e0 = r0.x, p0 = r0.y;            // p-e multiple of 4
    int e1 = r1.x, p1 = r1.y;
    float A0 = 0.f, A1 = 0.f, A2 = 0.f, A3 = 0.f;
    float B0 = 0.f, B1 = 0.f, B2 = 0.f, B3 = 0.f;

#define GR(m) (*(const uint2*)(hrow + (size_t)(m) * 64))
#define GACCA(u)                                                            \
    A0 += bflo(u.x); A1 += bfhi(u.x); A2 += bflo(u.y); A3 += bfhi(u.y);
#define GACCB(u)                                                            \
    B0 += bflo(u.x); B1 += bfhi(u.x); B2 += bflo(u.y); B3 += bfhi(u.y);

    while (p0 - e0 > 32) {               // rare (P(deg>32) ~ 2e-4)
        int d0 = col[e0 + g],      d1 = col[e0 + 4 + g];
        int d2 = col[e0 + 8 + g],  d3 = col[e0 + 12 + g];
        int d4 = col[e0 + 16 + g], d5 = col[e0 + 20 + g];
        int d6 = col[e0 + 24 + g], d7 = col[e0 + 28 + g];
        uint2 v0 = GR(d0), v1 = GR(d1), v2 = GR(d2), v3 = GR(d3);
        uint2 v4 = GR(d4), v5 = GR(d5), v6 = GR(d6), v7 = GR(d7);
        GACCA(v0) GACCA(v1) GACCA(v2) GACCA(v3)
        GACCA(v4) GACCA(v5) GACCA(v6) GACCA(v7)
        e0 += 32;
    }
    while (p1 - e1 > 32) {
        int d0 = col[e1 + g],      d1 = col[e1 + 4 + g];
        int d2 = col[e1 + 8 + g],  d3 = col[e1 + 12 + g];
        int d4 = col[e1 + 16 + g], d5 = col[e1 + 20 + g];
        int d6 = col[e1 + 24 + g], d7 = col[e1 + 28 + g];
        uint2 v0 = GR(d0), v1 = GR(d1), v2 = GR(d2), v3 = GR(d3);
        uint2 v4 = GR(d4), v5 = GR(d5), v6 = GR(d6), v7 = GR(d7);
        GACCB(v0) GACCB(v1) GACCB(v2) GACCB(v3)
        GACCB(v4) GACCB(v5) GACCB(v6) GACCB(v7)
        e1 += 32;
    }
    int rem0 = p0 - e0, rem1 = p1 - e1;  // 0..32, multiples of 4
    bool t0 = rem0 > 16, t1 = rem1 > 16; // wave-uniform tiers
    // batched col loads for both nodes (tier-1 always; tier-2 conditional)
    int c00 = col[e0 + g],     c01 = col[e0 + 4 + g];
    int c02 = col[e0 + 8 + g], c03 = col[e0 + 12 + g];
    int c10 = col[e1 + g],     c11 = col[e1 + 4 + g];
    int c12 = col[e1 + 8 + g], c13 = col[e1 + 12 + g];
    int c04 = 0, c05 = 0, c06 = 0, c07 = 0;
    int c14 = 0, c15 = 0, c16 = 0, c17 = 0;
    if (t0) {
        c04 = col[e0 + 16 + g]; c05 = col[e0 + 20 + g];
        c06 = col[e0 + 24 + g]; c07 = col[e0 + 28 + g];
    }
    if (t1) {
        c14 = col[e1 + 16 + g]; c15 = col[e1 + 20 + g];
        c16 = col[e1 + 24 + g]; c17 = col[e1 + 28 + g];
    }
    // masks -> gathers, all batch-issued
    int m00 = (g < rem0)      ? c00 : n;
    int m01 = (4 + g < rem0)  ? c01 : n;
    int m02 = (8 + g < rem0)  ? c02 : n;
    int m03 = (12 + g < rem0) ? c03 : n;
    int m10 = (g < rem1)      ? c10 : n;
    int m11 = (4 + g < rem1)  ? c11 : n;
    int m12 = (8 + g < rem1)  ? c12 : n;
    int m13 = (12 + g < rem1) ? c13 : n;
    uint2 u00 = GR(m00), u01 = GR(m01), u02 = GR(m02), u03 = GR(m03);
    uint2 u10 = GR(m10), u11 = GR(m11), u12 = GR(m12), u13 = GR(m13);
    if (t0) {
        int m04 = (16 + g < rem0) ? c04 : n;
        int m05 = (20 + g < rem0) ? c05 : n;
        int m06 = (24 + g < rem0) ? c06 : n;
        int m07 = (28 + g < rem0) ? c07 : n;
        uint2 u04 = GR(m04), u05 = GR(m05), u06 = GR(m06), u07 = GR(m07);
        GACCA(u04) GACCA(u05) GACCA(u06) GACCA(u07)
    }
    if (t1) {
        int m14 = (16 + g < rem1) ? c14 : n;
        int m15 = (20 + g < rem1) ? c15 : n;
        int m16 = (24 + g < rem1) ? c16 : n;
        int m17 = (28 + g < rem1) ? c17 : n;
        uint2 u14 = GR(m14), u15 = GR(m15), u16 = GR(m16), u17 = GR(m17);
        GACCB(u14) GACCB(u15) GACCB(u16) GACCB(u17)
    }
    GACCA(u00) GACCA(u01) GACCA(u02) GACCA(u03)
    GACCB(u10) GACCB(u11) GACCB(u12) GACCB(u13)
#undef GR
#undef GACCA
#undef GACCB

    A0 += __shfl_xor(A0, 16); A0 += __shfl_xor(A0, 32);
    A1 += __shfl_xor(A1, 16); A1 += __shfl_xor(A1, 32);
    A2 += __shfl_xor(A2, 16); A2 += __shfl_xor(A2, 32);
    A3 += __shfl_xor(A3, 16); A3 += __shfl_xor(A3, 32);
    B0 += __shfl_xor(B0, 16); B0 += __shfl_xor(B0, 32);
    B1 += __shfl_xor(B1, 16); B1 += __shfl_xor(B1, 32);
    B2 += __shfl_xor(B2, 16); B2 += __shfl_xor(B2, 32);
    B3 += __shfl_xor(B3, 16); B3 += __shfl_xor(B3, 32);

    if (lane < 16) {
        float o0 = A0 + bflo(us0.x), o1 = A1 + bfhi(us0.x);
        float o2 = A2 + bflo(us0.y), o3 = A3 + bfhi(us0.y);
        float4 bv = *(const float4*)(bias + c4 * 4);
        o0 = sc0 * o0 + bv.x; o1 = sc0 * o1 + bv.y;
        o2 = sc0 * o2 + bv.z; o3 = sc0 * o3 + bv.w;
        if (RELU) {
            o0 = fmaxf(o0, 0.f); o1 = fmaxf(o1, 0.f);
            o2 = fmaxf(o2, 0.f); o3 = fmaxf(o3, 0.f);
        }
        if (F32OUT) {
            uint2 rb = *(const uint2*)(residb + (size_t)node0 * 64 + c4 * 4);
            o0 += bflo(rb.x); o1 += bfhi(rb.x);
            o2 += bflo(rb.y); o3 += bfhi(rb.y);
            *(float4*)(outf + (size_t)node0 * 64 + c4 * 4) =
                make_float4(o0, o1, o2, o3);
        } else {
            unsigned w0 = f2bf(o0) | (f2bf(o1) << 16);
            unsigned w1 = f2bf(o2) | (f2bf(o3) << 16);
            *(uint2*)(outb + (size_t)node0 * 64 + c4 * 4) = make_uint2(w0, w1);
        }
    } else if (lane < 32 && has1) {
        float o0 = B0 + bflo(us1.x), o1 = B1 + bfhi(us1.x);
        float o2 = B2 + bflo(us1.y), o3 = B3 + bfhi(us1.y);
        float4 bv = *(const float4*)(bias + c4 * 4);
        o0 = sc1 * o0 + bv.x; o1 = sc1 * o1 + bv.y;
        o2 = sc1 * o2 + bv.z; o3 = sc1 * o3 + bv.w;
        if (RELU) {
            o0 = fmaxf(o0, 0.f); o1 = fmaxf(o1, 0.f);
            o2 = fmaxf(o2, 0.f); o3 = fmaxf(o3, 0.f);
        }
        if (F32OUT) {
            uint2 rb = *(const uint2*)(residb + (size_t)node1 * 64 + c4 * 4);
            o0 += bflo(rb.x); o1 += bfhi(rb.x);
            o2 += bflo(rb.y); o3 += bfhi(rb.y);
            *(float4*)(outf + (size_t)node1 * 64 + c4 * 4) =
                make_float4(o0, o1, o2, o3);
        } else {
            unsigned w0 = f2bf(o0) | (f2bf(o1) << 16);
            unsigned w1 = f2bf(o2) | (f2bf(o3) << 16);
            *(uint2*)(outb + (size_t)node1 * 64 + c4 * 4) = make_uint2(w0, w1);
        }
    }
}

// ---------------------------------------------------------------------------
extern "C" void kernel_launch(void* const* d_in, const int* in_sizes, int n_in,
                              void* d_out, int out_size, void* d_ws, size_t ws_size,
                              hipStream_t stream) {
    const float* x  = (const float*)d_in[0];
    const int*   ei = (const int*)d_in[1];
    const float* W0 = (const float*)d_in[2];
    const float* b0 = (const float*)d_in[3];
    const float* Ws = (const float*)d_in[4];
    const float* bs = (const float*)d_in[5];
    float* out = (float*)d_out;

    const int N = in_sizes[0] / 128;
    const int E = in_sizes[1] / 2;
    const int B = (N + BKN - 1) >> LB;

    char* p = (char*)d_ws;
    auto carve = [&](size_t bytes) {
        char* r = p;
        p += (bytes + 255) & ~(size_t)255;
        return r;
    };
    int*      bucketCursor = (int*)carve(512 * 4);
    unsigned* packed       = (unsigned*)carve((size_t)B * CAP * 4);
    int*      col          = (int*)carve(((size_t)B * CAPCOL + 64) * 4);  // +guard
    int2*     rp2          = (int2*)carve((size_t)N * 8);
    float*    dinv         = (float*)carve((size_t)N * 4);
    ushort_t* hs           = (ushort_t*)carve((size_t)(N + 1) * 64 * 2); // +sentinel
    ushort_t* xtb          = (ushort_t*)carve((size_t)N * 64 * 2);
    ushort_t* hb           = (ushort_t*)carve((size_t)N * 64 * 2);

    hipMemsetAsync(bucketCursor, 0, 512 * 4, stream);

    k_scatter<<<(E + CHUNK - 1) / CHUNK, 256, 0, stream>>>(ei, E, bucketCursor, packed);
    k_sort<<<B, 256, 0, stream>>>(packed, bucketCursor, col, rp2, dinv, hs, N);

    int gb = (N + 127) / 128;
    int ablocks = (N + 7) / 8;   // 2 nodes/wave, 4 waves/block

    // layer 1: hs = (x @ W0) * dinv ; agg1 -> xtb (bf16, +b0, no relu)
    k_gemm1<<<gb, 256, 0, stream>>>(x, W0, dinv, hs, N);
    k_agg2n<0, 0><<<ablocks, 256, 0, stream>>>(hs, dinv, b0, col, rp2,
                                               nullptr, nullptr, xtb, N);
    // layer 2: hs = (xtb @ Ws0) * dinv ; agg2 -> hb (bf16, +bs0, relu)
    k_gemm64<<<gb, 256, 0, stream>>>(xtb, Ws, dinv, hs, N);
    k_agg2n<1, 0><<<ablocks, 256, 0, stream>>>(hs, dinv, bs, col, rp2,
                                               nullptr, nullptr, hb, N);
    // layer 3: hs = (hb @ Ws1) * dinv ; agg3 -> out (f32, +bs1, relu, +resid)
    k_gemm64<<<gb, 256, 0, stream>>>(hb, Ws + 64 * 64, dinv, hs, N);
    k_agg2n<1, 1><<<ablocks, 256, 0, stream>>>(hs, dinv, bs + 64, col, rp2,
                                               xtb, out, nullptr, N);
}